// Round 5
// baseline (234.212 us; speedup 1.0000x reference)
//
#include <hip/hip_runtime.h>

// PCEN: x [32, 256, 4096] fp32. EMA over time per row, then
// out = sqrt(x / (m+eps)^0.98 + 2) - sqrt(2).
//
// Wave-per-row, no barriers, no LDS, coalesced. Row held in registers as
// TWO software-pipelined halves (8+8 float4 per lane):
//   issue loads A (8x coalesced 1KB) -> issue loads B -> scan+epilogue+store A
//   (waits only on A via counted vmcnt, B still in flight) -> scan+epilogue+
//   store B. No vmcnt(0) drain anywhere; stores fire-and-forget.
// vs round 2 (85us, 2.36 TB/s): that version's __launch_bounds__(256,8)
// forced VGPR=32 -> no real prefetch, per-tile buffer rotation coupled
// store drain into the loop -> convoy phases at ~40% memory duty cycle.
// This version: plain __launch_bounds__(256) (no min-wave clause -- the
// forced-occupancy + high-liveness combo is the only construct that can
// make regalloc infeasible, and is dropped as a container-failure
// suspect), peak liveness ~64 data VGPRs falling to 32 after half A.
//
// Scan math (verified rounds 0-2): per-lane 4-elem local EMA (segment
// coeff A4 = 0.975^4), 6-step Hillis-Steele wave scan with coeffs
// A4^(2^d), 8-way ILP across sub-chunk scans, serial carry chain
// (coeff A256) fused with epilogue.

constexpr int T_LEN = 4096;
constexpr int LANES = 64;
constexpr int NSUB  = 16;               // sub-chunks of 256 elems (64 x float4)
constexpr int HALF  = 8;                // sub-chunks per pipeline half
constexpr int WAVES_PER_BLK = 4;
constexpr int NTHR  = LANES * WAVES_PER_BLK;

constexpr float EPSF = 1e-6f;
constexpr float SF   = 0.025f;
constexpr float A1F  = 0.975f;

// exact powers of 0.975 via constexpr repeated squaring
constexpr double dA1   = 0.975;
constexpr double dA2   = dA1 * dA1;
constexpr double dA4   = dA2 * dA2;     // per-lane segment coeff (4 steps)
constexpr double dA8   = dA4 * dA4;
constexpr double dA16  = dA8 * dA8;
constexpr double dA32  = dA16 * dA16;
constexpr double dA64  = dA32 * dA32;
constexpr double dA128 = dA64 * dA64;
constexpr double dA256 = dA128 * dA128; // per-sub-chunk coeff (64 lanes x 4)

__global__ __launch_bounds__(NTHR) void pcen_wave_kernel(
    const float* __restrict__ x, float* __restrict__ out, int rows)
{
    const int lane = threadIdx.x & 63;
    const int wave = threadIdx.x >> 6;
    const int row  = blockIdx.x * WAVES_PER_BLK + wave;
    if (row >= rows) return;

    const long long base = (long long)row * T_LEN;
    const float4* __restrict__ px   = (const float4*)(x + base);
    float4* __restrict__       pout = (float4*)(out + base);

    const float cA4   = (float)dA4;
    const float cA8   = (float)dA8;
    const float cA16  = (float)dA16;
    const float cA32  = (float)dA32;
    const float cA64  = (float)dA64;
    const float cA128 = (float)dA128;
    const float cA256 = (float)dA256;

    // lane-constant carry decay: A4^lane (lane's segment starts 4*lane steps in)
    float flane = 1.0f;
    if (lane & 1)  flane *= cA4;
    if (lane & 2)  flane *= cA8;
    if (lane & 4)  flane *= cA16;
    if (lane & 8)  flane *= cA32;
    if (lane & 16) flane *= cA64;
    if (lane & 32) flane *= cA128;

    const float SQRT_D = 1.41421356237309515f;  // sqrt(2.0)

    // ---- issue ALL row loads up front: half A then half B ----
    float4 dA_[HALF];
#pragma unroll
    for (int s = 0; s < HALF; ++s) dA_[s] = px[s * LANES + lane];
    float4 dB_[HALF];
#pragma unroll
    for (int s = 0; s < HALF; ++s) dB_[s] = px[(HALF + s) * LANES + lane];

    float carry = 0.0f;  // EMA value at end of previous sub-chunk

    // ================= half A (waits only on A loads) =================
    {
        float Sv[HALF];
#pragma unroll
        for (int s = 0; s < HALF; ++s) {
            float m = SF * dA_[s].x;
            m = fmaf(A1F, m, SF * dA_[s].y);
            m = fmaf(A1F, m, SF * dA_[s].z);
            m = fmaf(A1F, m, SF * dA_[s].w);
            Sv[s] = m;
        }
#pragma unroll
        for (int s = 0; s < HALF; ++s) {
            float tt;
            tt = __shfl_up(Sv[s], 1,  64); if (lane >= 1)  Sv[s] = fmaf(cA4,   tt, Sv[s]);
            tt = __shfl_up(Sv[s], 2,  64); if (lane >= 2)  Sv[s] = fmaf(cA8,   tt, Sv[s]);
            tt = __shfl_up(Sv[s], 4,  64); if (lane >= 4)  Sv[s] = fmaf(cA16,  tt, Sv[s]);
            tt = __shfl_up(Sv[s], 8,  64); if (lane >= 8)  Sv[s] = fmaf(cA32,  tt, Sv[s]);
            tt = __shfl_up(Sv[s], 16, 64); if (lane >= 16) Sv[s] = fmaf(cA64,  tt, Sv[s]);
            tt = __shfl_up(Sv[s], 32, 64); if (lane >= 32) Sv[s] = fmaf(cA128, tt, Sv[s]);
        }
#pragma unroll
        for (int s = 0; s < HALF; ++s) {
            float excl = __shfl_up(Sv[s], 1, 64);
            if (lane == 0) excl = 0.0f;
            float last = __shfl(Sv[s], 63, 64);

            float m = fmaf(flane, carry, excl);   // EMA just before lane's segment
            carry   = fmaf(cA256, carry, last);   // EMA at end of this sub-chunk

            float4 v = dA_[s];
            float4 o;
            m = fmaf(A1F, m, SF * v.x);
            o.x = __builtin_amdgcn_sqrtf(
                      fmaf(v.x, __builtin_amdgcn_exp2f(
                          -0.98f * __builtin_amdgcn_logf(m + EPSF)), 2.0f)) - SQRT_D;
            m = fmaf(A1F, m, SF * v.y);
            o.y = __builtin_amdgcn_sqrtf(
                      fmaf(v.y, __builtin_amdgcn_exp2f(
                          -0.98f * __builtin_amdgcn_logf(m + EPSF)), 2.0f)) - SQRT_D;
            m = fmaf(A1F, m, SF * v.z);
            o.z = __builtin_amdgcn_sqrtf(
                      fmaf(v.z, __builtin_amdgcn_exp2f(
                          -0.98f * __builtin_amdgcn_logf(m + EPSF)), 2.0f)) - SQRT_D;
            m = fmaf(A1F, m, SF * v.w);
            o.w = __builtin_amdgcn_sqrtf(
                      fmaf(v.w, __builtin_amdgcn_exp2f(
                          -0.98f * __builtin_amdgcn_logf(m + EPSF)), 2.0f)) - SQRT_D;

            pout[s * LANES + lane] = o;
        }
    }

    // ================= half B (loads were in flight under half A) =================
    {
        float Sv[HALF];
#pragma unroll
        for (int s = 0; s < HALF; ++s) {
            float m = SF * dB_[s].x;
            m = fmaf(A1F, m, SF * dB_[s].y);
            m = fmaf(A1F, m, SF * dB_[s].z);
            m = fmaf(A1F, m, SF * dB_[s].w);
            Sv[s] = m;
        }
#pragma unroll
        for (int s = 0; s < HALF; ++s) {
            float tt;
            tt = __shfl_up(Sv[s], 1,  64); if (lane >= 1)  Sv[s] = fmaf(cA4,   tt, Sv[s]);
            tt = __shfl_up(Sv[s], 2,  64); if (lane >= 2)  Sv[s] = fmaf(cA8,   tt, Sv[s]);
            tt = __shfl_up(Sv[s], 4,  64); if (lane >= 4)  Sv[s] = fmaf(cA16,  tt, Sv[s]);
            tt = __shfl_up(Sv[s], 8,  64); if (lane >= 8)  Sv[s] = fmaf(cA32,  tt, Sv[s]);
            tt = __shfl_up(Sv[s], 16, 64); if (lane >= 16) Sv[s] = fmaf(cA64,  tt, Sv[s]);
            tt = __shfl_up(Sv[s], 32, 64); if (lane >= 32) Sv[s] = fmaf(cA128, tt, Sv[s]);
        }
#pragma unroll
        for (int s = 0; s < HALF; ++s) {
            float excl = __shfl_up(Sv[s], 1, 64);
            if (lane == 0) excl = 0.0f;
            float last = __shfl(Sv[s], 63, 64);

            float m = fmaf(flane, carry, excl);
            carry   = fmaf(cA256, carry, last);

            float4 v = dB_[s];
            float4 o;
            m = fmaf(A1F, m, SF * v.x);
            o.x = __builtin_amdgcn_sqrtf(
                      fmaf(v.x, __builtin_amdgcn_exp2f(
                          -0.98f * __builtin_amdgcn_logf(m + EPSF)), 2.0f)) - SQRT_D;
            m = fmaf(A1F, m, SF * v.y);
            o.y = __builtin_amdgcn_sqrtf(
                      fmaf(v.y, __builtin_amdgcn_exp2f(
                          -0.98f * __builtin_amdgcn_logf(m + EPSF)), 2.0f)) - SQRT_D;
            m = fmaf(A1F, m, SF * v.z);
            o.z = __builtin_amdgcn_sqrtf(
                      fmaf(v.z, __builtin_amdgcn_exp2f(
                          -0.98f * __builtin_amdgcn_logf(m + EPSF)), 2.0f)) - SQRT_D;
            m = fmaf(A1F, m, SF * v.w);
            o.w = __builtin_amdgcn_sqrtf(
                      fmaf(v.w, __builtin_amdgcn_exp2f(
                          -0.98f * __builtin_amdgcn_logf(m + EPSF)), 2.0f)) - SQRT_D;

            pout[(HALF + s) * LANES + lane] = o;
        }
    }
}

extern "C" void kernel_launch(void* const* d_in, const int* in_sizes, int n_in,
                              void* d_out, int out_size, void* d_ws, size_t ws_size,
                              hipStream_t stream) {
    const float* x = (const float*)d_in[0];
    float* out = (float*)d_out;
    const int rows = in_sizes[0] / T_LEN;  // 32*256 = 8192
    const int blocks = (rows + WAVES_PER_BLK - 1) / WAVES_PER_BLK;
    pcen_wave_kernel<<<dim3(blocks), dim3(NTHR), 0, stream>>>(x, out, rows);
}